// Round 5
// baseline (386.334 us; speedup 1.0000x reference)
//
#include <hip/hip_runtime.h>
#include <hip/hip_bf16.h>
#include <cstdint>

// Problem dims (fixed): B=2, S=2048, E=1024, H=16, D=64
#define PB 2
#define PS 2048
#define PE 1024
#define PH 16
#define PD 64

typedef __attribute__((ext_vector_type(8))) short short8;
typedef __attribute__((ext_vector_type(8))) ushort u16x8;
typedef __attribute__((ext_vector_type(4))) float f32x4;

static __device__ __forceinline__ float bf2f(ushort u) {
  return __uint_as_float(((unsigned)u) << 16);
}
static __device__ __forceinline__ ushort f2bf(float f) {
  unsigned u = __float_as_uint(f);
  u += 0x7fffu + ((u >> 16) & 1u);   // RNE
  return (ushort)(u >> 16);
}
// packed f32x2 -> bf16x2 (v_cvt_pk_bf16_f32 on gfx950 via HIP API)
static __device__ __forceinline__ unsigned pkbf(float a, float b) {
  __hip_bfloat162 h = __float22bfloat162_rn(make_float2(a, b));
  return *reinterpret_cast<unsigned*>(&h);
}
static __device__ __forceinline__ u16x8 cvt8(f32x4 a, f32x4 b) {
  union { unsigned u[4]; u16x8 v; } r;
  r.u[0] = pkbf(a[0], a[1]); r.u[1] = pkbf(a[2], a[3]);
  r.u[2] = pkbf(b[0], b[1]); r.u[3] = pkbf(b[2], b[3]);
  return r.v;
}

// CK-idiom async global->LDS 16B copy. LDS dest must be wave-uniform base.
// NOTE (R6/R9): this async path is load-bearing for the GEMM core — fp32-A
// in-staging via VGPR+ds_write regressed twice (HBM blowup R6; pipeline
// serialization + 8-way ds_write conflicts R9). Keep async16 + bf16 pre-cvt.
static __device__ __forceinline__ void async16(void* lds, const void* g) {
  __attribute__((address_space(3))) unsigned* l =
      reinterpret_cast<__attribute__((address_space(3))) unsigned*>(
          reinterpret_cast<uintptr_t>(lds));
  const __attribute__((address_space(1))) unsigned* gp =
      reinterpret_cast<const __attribute__((address_space(1))) unsigned*>(
          reinterpret_cast<uintptr_t>(g));
  __builtin_amdgcn_global_load_lds(gp, l, 16, 0, 0);
}

// ---------------------------------------------------------------------------
// fp32 -> bf16 pre-conversion (x tensors + weights). blockIdx.y selects.
// 16 elems/thread.
// ---------------------------------------------------------------------------
__global__ __launch_bounds__(256)
void cvt_kernel(const float* __restrict__ s0, const float* __restrict__ s1,
                const float* __restrict__ s2, const float* __restrict__ s3,
                const float* __restrict__ s4, const float* __restrict__ s5,
                const float* __restrict__ s6,
                ushort* d0, ushort* d1, ushort* d2, ushort* d3, ushort* d4,
                ushort* d5, ushort* d6) {
  const int t = blockIdx.y;
  const float* src = t == 0 ? s0 : t == 1 ? s1 : t == 2 ? s2 : t == 3 ? s3
                   : t == 4 ? s4 : t == 5 ? s5 : s6;
  ushort* dst = t == 0 ? d0 : t == 1 ? d1 : t == 2 ? d2 : t == 3 ? d3
              : t == 4 ? d4 : t == 5 ? d5 : d6;
  const size_t n = (t < 3) ? (size_t)4194304 : (size_t)1048576;
  const size_t i0 = ((size_t)blockIdx.x * 256 + threadIdx.x) * 16;
  if (i0 >= n) return;
  const f32x4 a = *(const f32x4*)(src + i0);
  const f32x4 b = *(const f32x4*)(src + i0 + 4);
  const f32x4 c = *(const f32x4*)(src + i0 + 8);
  const f32x4 d = *(const f32x4*)(src + i0 + 12);
  *(u16x8*)(dst + i0) = cvt8(a, b);
  *(u16x8*)(dst + i0 + 8) = cvt8(c, d);
}

// ---------------------------------------------------------------------------
// GEMM core, bf16 A: BM=BN=128, BK=32, 4 waves 2x2, DOUBLE-BUFFERED LDS
// (minimum 2-phase per T3): issue tile t+1's global_load_lds BEFORE computing
// tile t, single barrier per K-step at the end (its implicit vmcnt(0) both
// guarantees t+1's data landed and fences the buf overwrite at t+2).
// SWAP=false: acc[i][j] = C[m=x-rows i][n=W-rows j] (normal).
// SWAP=true : acc[i][j] = C[m=W-rows j][n=x-rows i] (transposed output).
// ---------------------------------------------------------------------------
template <bool SWAP>
__device__ __forceinline__ void gemm_core(const ushort* __restrict__ A,
                                          const ushort* __restrict__ W,
                                          int m0, int n0,
                                          ushort* As, ushort* Bs,
                                          f32x4 acc[4][4]) {
  const int tid  = threadIdx.x;
  const int wave = tid >> 6;
  const int lane = tid & 63;
  const int quad = lane >> 4;
  const int lrow = lane & 15;
  const int wm = wave >> 1;
  const int wn = wave & 1;
  const int row0 = tid >> 2;
  const int kc8  = (tid & 3) * 8;

  // stage tile (kt) into buffer buf
  auto stage = [&](int buf, int kt) {
    ushort* Ab = As + buf * 4096;
    ushort* Bb = Bs + buf * 4096;
    async16(Ab + (size_t)wave * 512,        A + (size_t)(m0 + row0)      * PE + kt + kc8);
    async16(Ab + 2048 + (size_t)wave * 512, A + (size_t)(m0 + row0 + 64) * PE + kt + kc8);
    async16(Bb + (size_t)wave * 512,        W + (size_t)(n0 + row0)      * PE + kt + kc8);
    async16(Bb + 2048 + (size_t)wave * 512, W + (size_t)(n0 + row0 + 64) * PE + kt + kc8);
  };

  stage(0, 0);
  __syncthreads();          // prologue drain: tile 0 resident
  int cur = 0;

  for (int kt = 0; kt < PE; kt += 32) {
    if (kt + 32 < PE) stage(cur ^ 1, kt + 32);   // in flight during compute
    const ushort* Ab = As + cur * 4096;
    short8 af[4], bf[4];
#pragma unroll
    for (int i = 0; i < 4; ++i) {
      af[i] = *(const short8*)(Ab + (wm * 64 + i * 16 + lrow) * 32 + quad * 8);
      bf[i] = *(const short8*)(Bs + cur * 4096 + (wn * 64 + i * 16 + lrow) * 32 + quad * 8);
    }
#pragma unroll
    for (int i = 0; i < 4; ++i)
#pragma unroll
      for (int j = 0; j < 4; ++j) {
        if (SWAP)
          acc[i][j] = __builtin_amdgcn_mfma_f32_16x16x32_bf16(bf[j], af[i], acc[i][j], 0, 0, 0);
        else
          acc[i][j] = __builtin_amdgcn_mfma_f32_16x16x32_bf16(af[i], bf[j], acc[i][j], 0, 0, 0);
      }
    __syncthreads();        // implicit vmcnt(0): t+1 landed; reads of cur done
    cur ^= 1;
  }
}

// ---------------------------------------------------------------------------
// Fused QKV projection (bf16 x, bf16 W). Q,K -> [B,H,S,D]; V -> [B,H,D,S].
// Grid (x=m0, y=which*8+n0): n0-siblings sharing an A-strip land on the same
// XCD (ids differ by 32 == 0 mod 8) -> A served from that XCD's L2.
// ---------------------------------------------------------------------------
__global__ __launch_bounds__(256)
void qkv_kernel(const ushort* __restrict__ q, const ushort* __restrict__ k,
                const ushort* __restrict__ v,
                const ushort* __restrict__ Wq, const ushort* __restrict__ Wk,
                const ushort* __restrict__ Wv,
                const float* __restrict__ bq, const float* __restrict__ bk,
                const float* __restrict__ bv,
                ushort* __restrict__ qh, ushort* __restrict__ kh,
                ushort* __restrict__ vt) {
  __shared__ __align__(16) ushort As[2 * 128 * 32];
  __shared__ __align__(16) ushort Bs[2 * 128 * 32];
  const int which = blockIdx.y >> 3;
  const int n0 = (blockIdx.y & 7) * 128;
  const int m0 = blockIdx.x * 128;
  const ushort* A  = which == 0 ? q  : (which == 1 ? k  : v);
  const ushort* W  = which == 0 ? Wq : (which == 1 ? Wk : Wv);
  const float* bi  = which == 0 ? bq : (which == 1 ? bk : bv);

  const int lane = threadIdx.x & 63;
  const int wave = threadIdx.x >> 6;
  const int quad = lane >> 4, lrow = lane & 15;
  const int wm = wave >> 1, wn = wave & 1;

  f32x4 acc[4][4] = {};
  if (which == 2) {
    gemm_core<true>(A, W, m0, n0, As, Bs, acc);
    // acc[i][j]: C[m=W-row tile j][n=x-row tile i]; col=lane&15 -> x-row,
    // row=quad*4+r -> W-row (d-col). Store V^T [B,H,D,S].
#pragma unroll
    for (int j = 0; j < 4; ++j) {
#pragma unroll
      for (int i = 0; i < 4; ++i) {
        const int xrow = m0 + wm * 64 + i * 16 + lrow;
        const int b = xrow >> 11, s = xrow & 2047;
#pragma unroll
        for (int r = 0; r < 4; ++r) {
          const int dcol = n0 + wn * 64 + j * 16 + quad * 4 + r;
          const int h = dcol >> 6, d = dcol & 63;
          vt[((size_t)((b << 4) + h) << 17) + ((size_t)d << 11) + s] =
              f2bf(acc[i][j][r] + bi[dcol]);
        }
      }
    }
  } else {
    gemm_core<false>(A, W, m0, n0, As, Bs, acc);
    ushort* Out = which == 0 ? qh : kh;
#pragma unroll
    for (int j = 0; j < 4; ++j) {
      const int col = n0 + wn * 64 + j * 16 + lrow;          // n in [0,1024)
      const float bias = bi[col];
      const int h = col >> 6, d = col & 63;
#pragma unroll
      for (int i = 0; i < 4; ++i)
#pragma unroll
        for (int r = 0; r < 4; ++r) {
          const int row = m0 + wm * 64 + i * 16 + quad * 4 + r;  // m in [0,4096)
          const int b = row >> 11, s = row & 2047;
          Out[((size_t)((b << 4) + h) << 17) + ((size_t)s << 6) + d] =
              f2bf(acc[i][j][r] + bias);
        }
    }
  }
}

// ---------------------------------------------------------------------------
// Output projection: out = ctx @ Wo^T + bo -> fp32 [4096,1024].
// Grid (x=m0 32, y=n0 8): n0-siblings same XCD (ids differ by 32).
// ---------------------------------------------------------------------------
__global__ __launch_bounds__(256)
void outproj_kernel(const ushort* __restrict__ ctx, const ushort* __restrict__ Wo,
                    const float* __restrict__ bo, float* __restrict__ out) {
  __shared__ __align__(16) ushort As[2 * 128 * 32];
  __shared__ __align__(16) ushort Bs[2 * 128 * 32];
  const int n0 = blockIdx.y * 128;
  const int m0 = blockIdx.x * 128;

  f32x4 acc[4][4] = {};
  gemm_core<false>(ctx, Wo, m0, n0, As, Bs, acc);

  const int lane = threadIdx.x & 63;
  const int wave = threadIdx.x >> 6;
  const int quad = lane >> 4, lrow = lane & 15;
  const int wm = wave >> 1, wn = wave & 1;
#pragma unroll
  for (int j = 0; j < 4; ++j) {
    const int col = n0 + wn * 64 + j * 16 + lrow;
    const float bias = bo[col];
#pragma unroll
    for (int i = 0; i < 4; ++i)
#pragma unroll
      for (int r = 0; r < 4; ++r) {
        const int row = m0 + wm * 64 + i * 16 + quad * 4 + r;
        out[((size_t)row << 10) + col] = acc[i][j][r] + bias;
      }
  }
}

// ---------------------------------------------------------------------------
// MFMA causal flash attention, S^T formulation, STATIC-OFFSET softmax,
// KEY-SPLIT wave decomposition (R4 post-mortem: LDS staging is load-bearing;
// R3's waste was 4 waves reading IDENTICAL K/V fragments + the P LDS
// round-trip). Each wave owns a 16-KEY slice x all 64 q rows:
//  - K/V LDS fragment reads drop 4x (2KB K + 2KB V per wave-tile).
//  - P never leaves the lane: QK S^T output regs (key=quad*4+r, q=ct*16+lrow)
//    ARE the PV B-fragment (k=quad*4+j, col=lrow). Two consecutive k-tiles
//    pair into full 16x16x32 PV MFMAs (k-order: 4 keys of tileA || 4 of
//    tileB; V A-frags read the same order as 2x 8B reads from the two live
//    V buffers). Odd tail: second half P=0.
//  - l per wave via ones-MFMA (R3-verified), partial over its key slice.
//  - Price: O/l are key-partial -> rotating 4-phase cross-wave LDS reduction
//    once per block; V triple-buffered (pair-PV reads buf kt-1, so the write
//    at kt+2 needs a third buffer). LDS 40KB -> 4 blocks/CU unchanged.
// Grid (32,32), balance perm (R3-verified): CU-sets {y,y+8,y+16,y+24} sum 62.
// ---------------------------------------------------------------------------
#define SW_IDX(r, g) (((r) << 6) + ((((g) ^ ((r) & 7))) << 3))
#define QSCALE 0.180336879f   /* 1/sqrt(64) * log2(e) */
#define SOFF 24.0f            /* static softmax offset (log2 domain) */

__global__ __launch_bounds__(256)
void attn_kernel(const ushort* __restrict__ qh, const ushort* __restrict__ kh,
                 const ushort* __restrict__ vt, ushort* __restrict__ ctx) {
  __shared__ __align__(16) ushort SMEM[20480];   // 40KB: Ks[2][4096] | Vs[3][4096]
  ushort* Ks = SMEM;
  ushort* Vs = SMEM + 8192;
  const int tid  = threadIdx.x;
  const int wave = tid >> 6;
  const int lane = tid & 63;
  const int quad = lane >> 4;
  const int lrow = lane & 15;
  const int bh = blockIdx.x, b = bh >> 4, h = bh & 15;
  const size_t base = (size_t)bh << 17;     // bh * S * D
  const int srow = tid >> 2;                // staging row 0..63
  const int sg0  = (tid & 3) * 2;           // staging granules sg0, sg0+1
  const int pr   = wave * 16 + lrow;        // epilogue q row (q-ownership)
  const int w16  = wave * 16;               // this wave's key-slice base

  // balance permutation: CU-resident {y,y+8,y+16,y+24} sum to 62
  const int y  = blockIdx.y;
  const int qb = (y < 8) ? 31 - y : (y < 16) ? y - 8 : (y < 24) ? 39 - y : y - 16;
  const int q0 = qb * 64;

  // Q B-fragments for ALL 4 q-subtiles (every wave needs all 64 q rows),
  // scaled by 1/sqrt(D)*log2(e). qf[ct][half]: q=ct*16+lrow, d=half*32+quad*8.
  short8 qf[4][2];
#pragma unroll
  for (int ct = 0; ct < 4; ++ct) {
    const ushort* qp = qh + base + (size_t)(q0 + ct * 16 + lrow) * 64 + quad * 8;
    const u16x8 a = *(const u16x8*)qp;
    const u16x8 c = *(const u16x8*)(qp + 32);
#pragma unroll
    for (int j = 0; j < 8; ++j) {
      qf[ct][0][j] = (short)f2bf(bf2f(a[j]) * QSCALE);
      qf[ct][1][j] = (short)f2bf(bf2f(c[j]) * QSCALE);
    }
  }

  // all-ones bf16 A-fragment for the l row-sum MFMA
  short8 ones;
#pragma unroll
  for (int j = 0; j < 8; ++j) ones[j] = (short)0x3F80;

  f32x4 o_acc[4][4] = {};   // [dt][ct]: d=dt*16+quad*4+reg, q=ct*16+lrow
  f32x4 lacc[4] = {};       // [ct]: partial l over this wave's key slice

  // prefetch tile 0 into registers (K rows = keys, V rows = d)
  u16x8 kst0, kst1, vst0, vst1;
  {
    const ushort* kp = kh + base + (size_t)srow * 64 + sg0 * 8;
    kst0 = *(const u16x8*)kp; kst1 = *(const u16x8*)(kp + 8);
    const ushort* vp = vt + base + (size_t)srow * 2048 + sg0 * 8;
    vst0 = *(const u16x8*)vp; vst1 = *(const u16x8*)(vp + 8);
  }

  uint2 pkA[4];             // packed P of the even tile of the current pair
  int vbuf = 0, vprev = 0;

  // pair-PV: A-frag j0-3 from VA (even tile keys w16+quad*4..+3),
  //          j4-7 from VB (odd tile, same cols); B-frag = {pkA, pkB}.
  auto do_pv = [&](const ushort* VA, const ushort* VB,
                   const uint2* A, const uint2* B) {
#pragma unroll
    for (int ct = 0; ct < 4; ++ct) {
      union { unsigned u[4]; short8 v; } pb;
      pb.u[0] = A[ct].x; pb.u[1] = A[ct].y;
      pb.u[2] = B[ct].x; pb.u[3] = B[ct].y;
      lacc[ct] = __builtin_amdgcn_mfma_f32_16x16x32_bf16(ones, pb.v, lacc[ct], 0, 0, 0);
#pragma unroll
      for (int dt = 0; dt < 4; ++dt) {
        const int row = dt * 16 + lrow;
        const int off = (row << 6) +
                        (((w16 >> 3) + (quad >> 1) ^ (row & 7)) << 3) +
                        ((quad & 1) << 2);
        union { uint2 u2[2]; short8 v; } va;
        va.u2[0] = *(const uint2*)(VA + off);
        va.u2[1] = *(const uint2*)(VB + off);
        o_acc[dt][ct] = __builtin_amdgcn_mfma_f32_16x16x32_bf16(va.v, pb.v, o_acc[dt][ct], 0, 0, 0);
      }
    }
  };

  for (int kt = 0; kt <= qb; ++kt) {
    const int kbuf = kt & 1;
    *(u16x8*)&Ks[kbuf * 4096 + SW_IDX(srow, sg0)]     = kst0;
    *(u16x8*)&Ks[kbuf * 4096 + SW_IDX(srow, sg0 + 1)] = kst1;
    *(u16x8*)&Vs[vbuf * 4096 + SW_IDX(srow, sg0)]     = vst0;
    *(u16x8*)&Vs[vbuf * 4096 + SW_IDX(srow, sg0 + 1)] = vst1;
    __syncthreads();   // single barrier per tile

    if (kt < qb) {     // early-issue next tile's global loads
      const ushort* kp = kh + base + (size_t)((kt + 1) * 64 + srow) * 64 + sg0 * 8;
      kst0 = *(const u16x8*)kp; kst1 = *(const u16x8*)(kp + 8);
      const ushort* vp = vt + base + (size_t)srow * 2048 + (kt + 1) * 64 + sg0 * 8;
      vst0 = *(const u16x8*)vp; vst1 = *(const u16x8*)(vp + 8);
    }

    // QK: S^T[key=w16+quad*4+r][q=ct*16+lrow], K-frags read ONCE (2KB/wave)
    const ushort* Kb = Ks + kbuf * 4096;
    const short8 kb0 = *(const short8*)&Kb[SW_IDX(w16 + lrow, quad)];
    const short8 kb1 = *(const short8*)&Kb[SW_IDX(w16 + lrow, quad + 4)];
    f32x4 st[4];
#pragma unroll
    for (int ct = 0; ct < 4; ++ct) {
      st[ct] = (f32x4){-SOFF, -SOFF, -SOFF, -SOFF};
      st[ct] = __builtin_amdgcn_mfma_f32_16x16x32_bf16(kb0, qf[ct][0], st[ct], 0, 0, 0);
      st[ct] = __builtin_amdgcn_mfma_f32_16x16x32_bf16(kb1, qf[ct][1], st[ct], 0, 0, 0);
    }

    if (kt == qb) {    // causal mask on diagonal tile (local coords)
#pragma unroll
      for (int ct = 0; ct < 4; ++ct)
#pragma unroll
        for (int r = 0; r < 4; ++r)
          if (w16 + quad * 4 + r > ct * 16 + lrow) st[ct][r] = -1e30f;
    }

    // static-offset softmax: p = exp2(st); pack to bf16 words in-lane
    uint2 pcur[4];
#pragma unroll
    for (int ct = 0; ct < 4; ++ct) {
      const float p0 = exp2f(st[ct][0]);
      const float p1 = exp2f(st[ct][1]);
      const float p2 = exp2f(st[ct][2]);
      const float p3 = exp2f(st[ct][3]);
      pcur[ct].x = pkbf(p0, p1); pcur[ct].y = pkbf(p2, p3);
    }

    if ((kt & 1) == 0) {
#pragma unroll
      for (int ct = 0; ct < 4; ++ct) pkA[ct] = pcur[ct];
      vprev = vbuf;
    } else {
      do_pv(Vs + vprev * 4096, Vs + vbuf * 4096, pkA, pcur);
    }
    vbuf = (vbuf == 2) ? 0 : vbuf + 1;
  }

  if ((qb & 1) == 0) {   // odd tile count: tail PV, second half P = 0
    uint2 z[4];
#pragma unroll
    for (int ct = 0; ct < 4; ++ct) { z[ct].x = 0u; z[ct].y = 0u; }
    do_pv(Vs + vprev * 4096, Vs + vprev * 4096, pkA, z);
  }

  // ---- cross-wave reduction: O (and l) are key-partial. Rotating 4-phase
  // add into Ored[64 q][68 d-padded] f32 (aliases Ks/Vs, dead now).
  __syncthreads();
  float* Ored = (float*)SMEM;              // 64*68*4 = 17408 B
  float* Lred = (float*)SMEM + 64 * 68;    // [4][64] f32
  if (quad == 0) {
#pragma unroll
    for (int ct = 0; ct < 4; ++ct)
      Lred[wave * 64 + ct * 16 + lrow] = lacc[ct][0];
  }
#pragma unroll
  for (int p = 0; p < 4; ++p) {
    const int ct = (wave + p) & 3;
#pragma unroll
    for (int dt = 0; dt < 4; ++dt) {
      float* pos = Ored + (ct * 16 + lrow) * 68 + dt * 16 + quad * 4;
      if (p == 0) {
        *(f32x4*)pos = o_acc[dt][ct];
      } else {
        f32x4 c = *(const f32x4*)pos;
        c += o_acc[dt][ct];
        *(f32x4*)pos = c;
      }
    }
    __syncthreads();
  }

  // epilogue (original q-ownership): lane -> q=pr, d=nt*16+quad*4+r
  const float l = Lred[pr] + Lred[64 + pr] + Lred[128 + pr] + Lred[192 + pr];
  const float inv = 1.f / l;
  const size_t rowb = ((size_t)b << 21) + ((size_t)(q0 + pr) << 10) + (h << 6);
#pragma unroll
  for (int nt = 0; nt < 4; ++nt) {
    const f32x4 o = *(const f32x4*)(Ored + pr * 68 + nt * 16 + quad * 4);
    uint2 u;
    u.x = pkbf(o[0] * inv, o[1] * inv);
    u.y = pkbf(o[2] * inv, o[3] * inv);
    *(uint2*)(ctx + rowb + nt * 16 + quad * 4) = u;
  }
}

// ---------------------------------------------------------------------------
extern "C" void kernel_launch(void* const* d_in, const int* in_sizes, int n_in,
                              void* d_out, int out_size, void* d_ws, size_t ws_size,
                              hipStream_t stream) {
  const float* q  = (const float*)d_in[0];
  const float* k  = (const float*)d_in[1];
  const float* v  = (const float*)d_in[2];
  // d_in[3] = causal mask (tril) — applied analytically, not read
  const float* Wq = (const float*)d_in[4];
  const float* bq = (const float*)d_in[5];
  const float* Wk = (const float*)d_in[6];
  const float* bk = (const float*)d_in[7];
  const float* Wv = (const float*)d_in[8];
  const float* bv = (const float*)d_in[9];
  const float* Wo = (const float*)d_in[10];
  const float* bo = (const float*)d_in[11];

  const size_t NTOK = (size_t)PB * PS * PE;   // 4,194,304 elems
  const size_t NW   = (size_t)PE * PE;        // 1,048,576 elems
  ushort* qh  = (ushort*)d_ws;
  ushort* kh  = qh + NTOK;
  ushort* vt  = kh + NTOK;
  ushort* qc  = vt + NTOK;
  ushort* kc  = qc + NTOK;
  ushort* vc  = kc + NTOK;
  ushort* wqc = vc + NTOK;
  ushort* wkc = wqc + NW;
  ushort* wvc = wkc + NW;
  ushort* woc = wvc + NW;
  ushort* ctx = qc;   // alias: qc is dead after qkv_kernel completes

  cvt_kernel<<<dim3(1024, 7), dim3(256), 0, stream>>>(
      q, k, v, Wq, Wk, Wv, Wo, qc, kc, vc, wqc, wkc, wvc, woc);
  qkv_kernel<<<dim3(32, 24), dim3(256), 0, stream>>>(
      qc, kc, vc, wqc, wkc, wvc, bq, bk, bv, qh, kh, vt);
  attn_kernel<<<dim3(32, 32), dim3(256), 0, stream>>>(qh, kh, vt, ctx);
  outproj_kernel<<<dim3(32, 8), dim3(256), 0, stream>>>(
      ctx, woc, bo, (float*)d_out);
}

// Round 6
// 262.406 us; speedup vs baseline: 1.4723x; 1.4723x over previous
//
#include <hip/hip_runtime.h>
#include <hip/hip_bf16.h>
#include <cstdint>

// Problem dims (fixed): B=2, S=2048, E=1024, H=16, D=64
#define PB 2
#define PS 2048
#define PE 1024
#define PH 16
#define PD 64

typedef __attribute__((ext_vector_type(8))) short short8;
typedef __attribute__((ext_vector_type(8))) ushort u16x8;
typedef __attribute__((ext_vector_type(4))) float f32x4;

static __device__ __forceinline__ float bf2f(ushort u) {
  return __uint_as_float(((unsigned)u) << 16);
}
static __device__ __forceinline__ ushort f2bf(float f) {
  unsigned u = __float_as_uint(f);
  u += 0x7fffu + ((u >> 16) & 1u);   // RNE
  return (ushort)(u >> 16);
}
// packed f32x2 -> bf16x2 (v_cvt_pk_bf16_f32 on gfx950 via HIP API)
static __device__ __forceinline__ unsigned pkbf(float a, float b) {
  __hip_bfloat162 h = __float22bfloat162_rn(make_float2(a, b));
  return *reinterpret_cast<unsigned*>(&h);
}
static __device__ __forceinline__ u16x8 cvt8(f32x4 a, f32x4 b) {
  union { unsigned u[4]; u16x8 v; } r;
  r.u[0] = pkbf(a[0], a[1]); r.u[1] = pkbf(a[2], a[3]);
  r.u[2] = pkbf(b[0], b[1]); r.u[3] = pkbf(b[2], b[3]);
  return r.v;
}

// CK-idiom async global->LDS 16B copy. LDS dest must be wave-uniform base.
static __device__ __forceinline__ void async16(void* lds, const void* g) {
  __attribute__((address_space(3))) unsigned* l =
      reinterpret_cast<__attribute__((address_space(3))) unsigned*>(
          reinterpret_cast<uintptr_t>(lds));
  const __attribute__((address_space(1))) unsigned* gp =
      reinterpret_cast<const __attribute__((address_space(1))) unsigned*>(
          reinterpret_cast<uintptr_t>(g));
  __builtin_amdgcn_global_load_lds(gp, l, 16, 0, 0);
}

// ---------------------------------------------------------------------------
// fp32 -> bf16 pre-conversion (x tensors + weights). blockIdx.y selects.
// 16 elems/thread.
// ---------------------------------------------------------------------------
__global__ __launch_bounds__(256)
void cvt_kernel(const float* __restrict__ s0, const float* __restrict__ s1,
                const float* __restrict__ s2, const float* __restrict__ s3,
                const float* __restrict__ s4, const float* __restrict__ s5,
                const float* __restrict__ s6,
                ushort* d0, ushort* d1, ushort* d2, ushort* d3, ushort* d4,
                ushort* d5, ushort* d6) {
  const int t = blockIdx.y;
  const float* src = t == 0 ? s0 : t == 1 ? s1 : t == 2 ? s2 : t == 3 ? s3
                   : t == 4 ? s4 : t == 5 ? s5 : s6;
  ushort* dst = t == 0 ? d0 : t == 1 ? d1 : t == 2 ? d2 : t == 3 ? d3
              : t == 4 ? d4 : t == 5 ? d5 : d6;
  const size_t n = (t < 3) ? (size_t)4194304 : (size_t)1048576;
  const size_t i0 = ((size_t)blockIdx.x * 256 + threadIdx.x) * 16;
  if (i0 >= n) return;
  const f32x4 a = *(const f32x4*)(src + i0);
  const f32x4 b = *(const f32x4*)(src + i0 + 4);
  const f32x4 c = *(const f32x4*)(src + i0 + 8);
  const f32x4 d = *(const f32x4*)(src + i0 + 12);
  *(u16x8*)(dst + i0) = cvt8(a, b);
  *(u16x8*)(dst + i0 + 8) = cvt8(c, d);
}

// ---------------------------------------------------------------------------
// GEMM core, bf16 A: BM=BN=128, BK=32, 4 waves 2x2, DOUBLE-BUFFERED LDS.
// ---------------------------------------------------------------------------
template <bool SWAP>
__device__ __forceinline__ void gemm_core(const ushort* __restrict__ A,
                                          const ushort* __restrict__ W,
                                          int m0, int n0,
                                          ushort* As, ushort* Bs,
                                          f32x4 acc[4][4]) {
  const int tid  = threadIdx.x;
  const int wave = tid >> 6;
  const int lane = tid & 63;
  const int quad = lane >> 4;
  const int lrow = lane & 15;
  const int wm = wave >> 1;
  const int wn = wave & 1;
  const int row0 = tid >> 2;
  const int kc8  = (tid & 3) * 8;

  auto stage = [&](int buf, int kt) {
    ushort* Ab = As + buf * 4096;
    ushort* Bb = Bs + buf * 4096;
    async16(Ab + (size_t)wave * 512,        A + (size_t)(m0 + row0)      * PE + kt + kc8);
    async16(Ab + 2048 + (size_t)wave * 512, A + (size_t)(m0 + row0 + 64) * PE + kt + kc8);
    async16(Bb + (size_t)wave * 512,        W + (size_t)(n0 + row0)      * PE + kt + kc8);
    async16(Bb + 2048 + (size_t)wave * 512, W + (size_t)(n0 + row0 + 64) * PE + kt + kc8);
  };

  stage(0, 0);
  __syncthreads();          // prologue drain: tile 0 resident
  int cur = 0;

  for (int kt = 0; kt < PE; kt += 32) {
    if (kt + 32 < PE) stage(cur ^ 1, kt + 32);   // in flight during compute
    const ushort* Ab = As + cur * 4096;
    short8 af[4], bf[4];
#pragma unroll
    for (int i = 0; i < 4; ++i) {
      af[i] = *(const short8*)(Ab + (wm * 64 + i * 16 + lrow) * 32 + quad * 8);
      bf[i] = *(const short8*)(Bs + cur * 4096 + (wn * 64 + i * 16 + lrow) * 32 + quad * 8);
    }
#pragma unroll
    for (int i = 0; i < 4; ++i)
#pragma unroll
      for (int j = 0; j < 4; ++j) {
        if (SWAP)
          acc[i][j] = __builtin_amdgcn_mfma_f32_16x16x32_bf16(bf[j], af[i], acc[i][j], 0, 0, 0);
        else
          acc[i][j] = __builtin_amdgcn_mfma_f32_16x16x32_bf16(af[i], bf[j], acc[i][j], 0, 0, 0);
      }
    __syncthreads();        // implicit vmcnt(0): t+1 landed; reads of cur done
    cur ^= 1;
  }
}

// ---------------------------------------------------------------------------
// Fused QKV projection (bf16 x, bf16 W). Q,K -> [B,H,S,D]; V -> [B,H,D,S].
// ---------------------------------------------------------------------------
__global__ __launch_bounds__(256)
void qkv_kernel(const ushort* __restrict__ q, const ushort* __restrict__ k,
                const ushort* __restrict__ v,
                const ushort* __restrict__ Wq, const ushort* __restrict__ Wk,
                const ushort* __restrict__ Wv,
                const float* __restrict__ bq, const float* __restrict__ bk,
                const float* __restrict__ bv,
                ushort* __restrict__ qh, ushort* __restrict__ kh,
                ushort* __restrict__ vt) {
  __shared__ __align__(16) ushort As[2 * 128 * 32];
  __shared__ __align__(16) ushort Bs[2 * 128 * 32];
  const int which = blockIdx.y >> 3;
  const int n0 = (blockIdx.y & 7) * 128;
  const int m0 = blockIdx.x * 128;
  const ushort* A  = which == 0 ? q  : (which == 1 ? k  : v);
  const ushort* W  = which == 0 ? Wq : (which == 1 ? Wk : Wv);
  const float* bi  = which == 0 ? bq : (which == 1 ? bk : bv);

  const int lane = threadIdx.x & 63;
  const int wave = threadIdx.x >> 6;
  const int quad = lane >> 4, lrow = lane & 15;
  const int wm = wave >> 1, wn = wave & 1;

  f32x4 acc[4][4] = {};
  if (which == 2) {
    gemm_core<true>(A, W, m0, n0, As, Bs, acc);
#pragma unroll
    for (int j = 0; j < 4; ++j) {
#pragma unroll
      for (int i = 0; i < 4; ++i) {
        const int xrow = m0 + wm * 64 + i * 16 + lrow;
        const int b = xrow >> 11, s = xrow & 2047;
#pragma unroll
        for (int r = 0; r < 4; ++r) {
          const int dcol = n0 + wn * 64 + j * 16 + quad * 4 + r;
          const int h = dcol >> 6, d = dcol & 63;
          vt[((size_t)((b << 4) + h) << 17) + ((size_t)d << 11) + s] =
              f2bf(acc[i][j][r] + bi[dcol]);
        }
      }
    }
  } else {
    gemm_core<false>(A, W, m0, n0, As, Bs, acc);
    ushort* Out = which == 0 ? qh : kh;
#pragma unroll
    for (int j = 0; j < 4; ++j) {
      const int col = n0 + wn * 64 + j * 16 + lrow;          // n in [0,1024)
      const float bias = bi[col];
      const int h = col >> 6, d = col & 63;
#pragma unroll
      for (int i = 0; i < 4; ++i)
#pragma unroll
        for (int r = 0; r < 4; ++r) {
          const int row = m0 + wm * 64 + i * 16 + quad * 4 + r;  // m in [0,4096)
          const int b = row >> 11, s = row & 2047;
          Out[((size_t)((b << 4) + h) << 17) + ((size_t)s << 6) + d] =
              f2bf(acc[i][j][r] + bias);
        }
    }
  }
}

// ---------------------------------------------------------------------------
// Output projection: out = ctx @ Wo^T + bo -> fp32 [4096,1024].
// ---------------------------------------------------------------------------
__global__ __launch_bounds__(256)
void outproj_kernel(const ushort* __restrict__ ctx, const ushort* __restrict__ Wo,
                    const float* __restrict__ bo, float* __restrict__ out) {
  __shared__ __align__(16) ushort As[2 * 128 * 32];
  __shared__ __align__(16) ushort Bs[2 * 128 * 32];
  const int n0 = blockIdx.y * 128;
  const int m0 = blockIdx.x * 128;

  f32x4 acc[4][4] = {};
  gemm_core<false>(ctx, Wo, m0, n0, As, Bs, acc);

  const int lane = threadIdx.x & 63;
  const int wave = threadIdx.x >> 6;
  const int quad = lane >> 4, lrow = lane & 15;
  const int wm = wave >> 1, wn = wave & 1;
#pragma unroll
  for (int j = 0; j < 4; ++j) {
    const int col = n0 + wn * 64 + j * 16 + lrow;
    const float bias = bo[col];
#pragma unroll
    for (int i = 0; i < 4; ++i)
#pragma unroll
      for (int r = 0; r < 4; ++r) {
        const int row = m0 + wm * 64 + i * 16 + quad * 4 + r;
        out[((size_t)row << 10) + col] = acc[i][j][r] + bias;
      }
  }
}

// ---------------------------------------------------------------------------
// MFMA causal flash attention, KEY-SPLIT wave decomposition (R5 algorithm,
// verified correct) with the SCRATCH SPILL FIXED (R5 post-mortem / rule #20:
// the rotating reduction indexed o_acc[dt][(wave+p)&3] -> runtime register
// index -> the whole 64-VGPR accumulator demoted to scratch -> 327MB/dispatch
// of spill traffic, all pipes idle).
// FIX: SLOT PERMUTATION. Wave w keeps q-subtile (w+s)&3 in accumulator SLOT s
// (compile-time). The permutation lives only in ADDRESSES (Q-load address,
// mask threshold, reduction LDS row, Lred row), which may be runtime. Every
// register array (qf, st, pcur, pkA, lacc, o_acc) is statically indexed
// everywhere; reduction phase p writes o_acc[dt][p] (static) into Ored rows
// of q-subtile (w+p)&3 (runtime LDS addr, conflict-free rotation preserved).
// Everything else from R5 unchanged: 16-key slice/wave (K/V LDS reads 4x
// lower than R3), P stays in-lane (QK output regs ARE the PV B-fragment,
// paired k-tiles), ones-MFMA l, triple-buffered V, 40KB LDS, balance perm.
// ---------------------------------------------------------------------------
#define SW_IDX(r, g) (((r) << 6) + ((((g) ^ ((r) & 7))) << 3))
#define QSCALE 0.180336879f   /* 1/sqrt(64) * log2(e) */
#define SOFF 24.0f            /* static softmax offset (log2 domain) */

__global__ __launch_bounds__(256)
void attn_kernel(const ushort* __restrict__ qh, const ushort* __restrict__ kh,
                 const ushort* __restrict__ vt, ushort* __restrict__ ctx) {
  __shared__ __align__(16) ushort SMEM[20480];   // 40KB: Ks[2][4096] | Vs[3][4096]
  ushort* Ks = SMEM;
  ushort* Vs = SMEM + 8192;
  const int tid  = threadIdx.x;
  const int wave = tid >> 6;
  const int lane = tid & 63;
  const int quad = lane >> 4;
  const int lrow = lane & 15;
  const int bh = blockIdx.x, b = bh >> 4, h = bh & 15;
  const size_t base = (size_t)bh << 17;     // bh * S * D
  const int srow = tid >> 2;                // staging row 0..63
  const int sg0  = (tid & 3) * 2;           // staging granules sg0, sg0+1
  const int pr   = wave * 16 + lrow;        // epilogue q row (q-ownership)
  const int w16  = wave * 16;               // this wave's key-slice base

  // balance permutation: CU-resident {y,y+8,y+16,y+24} sum to 62
  const int y  = blockIdx.y;
  const int qb = (y < 8) ? 31 - y : (y < 16) ? y - 8 : (y < 24) ? 39 - y : y - 16;
  const int q0 = qb * 64;

  // Slot s holds q-subtile (wave+s)&3. Register indices static; addresses
  // carry the permutation. qrow[s] (runtime VALUES, static slots) for mask.
  int qrow[4];
#pragma unroll
  for (int s = 0; s < 4; ++s) qrow[s] = ((wave + s) & 3) * 16 + lrow;

  // Q B-fragments, slot-permuted, scaled by 1/sqrt(D)*log2(e).
  short8 qf[4][2];
#pragma unroll
  for (int s = 0; s < 4; ++s) {
    const ushort* qp = qh + base + (size_t)(q0 + qrow[s]) * 64 + quad * 8;
    const u16x8 a = *(const u16x8*)qp;
    const u16x8 c = *(const u16x8*)(qp + 32);
#pragma unroll
    for (int j = 0; j < 8; ++j) {
      qf[s][0][j] = (short)f2bf(bf2f(a[j]) * QSCALE);
      qf[s][1][j] = (short)f2bf(bf2f(c[j]) * QSCALE);
    }
  }

  // all-ones bf16 A-fragment for the l row-sum MFMA
  short8 ones;
#pragma unroll
  for (int j = 0; j < 8; ++j) ones[j] = (short)0x3F80;

  f32x4 o_acc[4][4] = {};   // [dt][s]: d=dt*16+quad*4+reg, q=q0+qrow[s]
  f32x4 lacc[4] = {};       // [s]: partial l over this wave's key slice

  // prefetch tile 0 into registers (K rows = keys, V rows = d)
  u16x8 kst0, kst1, vst0, vst1;
  {
    const ushort* kp = kh + base + (size_t)srow * 64 + sg0 * 8;
    kst0 = *(const u16x8*)kp; kst1 = *(const u16x8*)(kp + 8);
    const ushort* vp = vt + base + (size_t)srow * 2048 + sg0 * 8;
    vst0 = *(const u16x8*)vp; vst1 = *(const u16x8*)(vp + 8);
  }

  uint2 pkA[4];             // packed P of the even tile of the current pair
  int vbuf = 0, vprev = 0;

  // pair-PV: A-frag j0-3 from VA (even tile keys w16+quad*4..+3),
  //          j4-7 from VB (odd tile, same cols); B-frag = {A, B} slot s.
  auto do_pv = [&](const ushort* VA, const ushort* VB,
                   const uint2* A, const uint2* B) {
#pragma unroll
    for (int s = 0; s < 4; ++s) {
      union { unsigned u[4]; short8 v; } pb;
      pb.u[0] = A[s].x; pb.u[1] = A[s].y;
      pb.u[2] = B[s].x; pb.u[3] = B[s].y;
      lacc[s] = __builtin_amdgcn_mfma_f32_16x16x32_bf16(ones, pb.v, lacc[s], 0, 0, 0);
#pragma unroll
      for (int dt = 0; dt < 4; ++dt) {
        const int row = dt * 16 + lrow;
        const int off = (row << 6) +
                        (((w16 >> 3) + (quad >> 1) ^ (row & 7)) << 3) +
                        ((quad & 1) << 2);
        union { uint2 u2[2]; short8 v; } va;
        va.u2[0] = *(const uint2*)(VA + off);
        va.u2[1] = *(const uint2*)(VB + off);
        o_acc[dt][s] = __builtin_amdgcn_mfma_f32_16x16x32_bf16(va.v, pb.v, o_acc[dt][s], 0, 0, 0);
      }
    }
  };

  for (int kt = 0; kt <= qb; ++kt) {
    const int kbuf = kt & 1;
    *(u16x8*)&Ks[kbuf * 4096 + SW_IDX(srow, sg0)]     = kst0;
    *(u16x8*)&Ks[kbuf * 4096 + SW_IDX(srow, sg0 + 1)] = kst1;
    *(u16x8*)&Vs[vbuf * 4096 + SW_IDX(srow, sg0)]     = vst0;
    *(u16x8*)&Vs[vbuf * 4096 + SW_IDX(srow, sg0 + 1)] = vst1;
    __syncthreads();   // single barrier per tile

    if (kt < qb) {     // early-issue next tile's global loads
      const ushort* kp = kh + base + (size_t)((kt + 1) * 64 + srow) * 64 + sg0 * 8;
      kst0 = *(const u16x8*)kp; kst1 = *(const u16x8*)(kp + 8);
      const ushort* vp = vt + base + (size_t)srow * 2048 + (kt + 1) * 64 + sg0 * 8;
      vst0 = *(const u16x8*)vp; vst1 = *(const u16x8*)(vp + 8);
    }

    // QK: S^T[key=w16+quad*4+r][q=qrow[s]], K-frags read ONCE (2KB/wave)
    const ushort* Kb = Ks + kbuf * 4096;
    const short8 kb0 = *(const short8*)&Kb[SW_IDX(w16 + lrow, quad)];
    const short8 kb1 = *(const short8*)&Kb[SW_IDX(w16 + lrow, quad + 4)];
    f32x4 st[4];
#pragma unroll
    for (int s = 0; s < 4; ++s) {
      st[s] = (f32x4){-SOFF, -SOFF, -SOFF, -SOFF};
      st[s] = __builtin_amdgcn_mfma_f32_16x16x32_bf16(kb0, qf[s][0], st[s], 0, 0, 0);
      st[s] = __builtin_amdgcn_mfma_f32_16x16x32_bf16(kb1, qf[s][1], st[s], 0, 0, 0);
    }

    if (kt == qb) {    // causal mask on diagonal tile (local coords)
#pragma unroll
      for (int s = 0; s < 4; ++s)
#pragma unroll
        for (int r = 0; r < 4; ++r)
          if (w16 + quad * 4 + r > qrow[s]) st[s][r] = -1e30f;
    }

    // static-offset softmax: p = exp2(st); pack to bf16 words in-lane
    uint2 pcur[4];
#pragma unroll
    for (int s = 0; s < 4; ++s) {
      const float p0 = exp2f(st[s][0]);
      const float p1 = exp2f(st[s][1]);
      const float p2 = exp2f(st[s][2]);
      const float p3 = exp2f(st[s][3]);
      pcur[s].x = pkbf(p0, p1); pcur[s].y = pkbf(p2, p3);
    }

    if ((kt & 1) == 0) {
#pragma unroll
      for (int s = 0; s < 4; ++s) pkA[s] = pcur[s];
      vprev = vbuf;
    } else {
      do_pv(Vs + vprev * 4096, Vs + vbuf * 4096, pkA, pcur);
    }
    vbuf = (vbuf == 2) ? 0 : vbuf + 1;
  }

  if ((qb & 1) == 0) {   // odd tile count: tail PV, second half P = 0
    uint2 z[4];
#pragma unroll
    for (int s = 0; s < 4; ++s) { z[s].x = 0u; z[s].y = 0u; }
    do_pv(Vs + vprev * 4096, Vs + vprev * 4096, pkA, z);
  }

  // ---- cross-wave reduction, rotation with STATIC register indices:
  // phase p (static): wave w writes SLOT p (= q-subtile (w+p)&3 -> runtime
  // LDS row, distinct across waves -> conflict-free). Ored aliases Ks/Vs.
  __syncthreads();
  float* Ored = (float*)SMEM;              // 64*68*4 = 17408 B
  float* Lred = (float*)SMEM + 64 * 68;    // [4][64] f32
  if (quad == 0) {
#pragma unroll
    for (int s = 0; s < 4; ++s)
      Lred[wave * 64 + qrow[s]] = lacc[s][0];
  }
#pragma unroll
  for (int p = 0; p < 4; ++p) {
#pragma unroll
    for (int dt = 0; dt < 4; ++dt) {
      float* pos = Ored + qrow[p] * 68 + dt * 16 + quad * 4;
      if (p == 0) {
        *(f32x4*)pos = o_acc[dt][0];
      } else {
        f32x4 c = *(const f32x4*)pos;
        c += o_acc[dt][p];
        *(f32x4*)pos = c;
      }
    }
    __syncthreads();
  }

  // epilogue (original q-ownership): lane -> q=pr, d=nt*16+quad*4+r
  const float l = Lred[pr] + Lred[64 + pr] + Lred[128 + pr] + Lred[192 + pr];
  const float inv = 1.f / l;
  const size_t rowb = ((size_t)b << 21) + ((size_t)(q0 + pr) << 10) + (h << 6);
#pragma unroll
  for (int nt = 0; nt < 4; ++nt) {
    const f32x4 o = *(const f32x4*)(Ored + pr * 68 + nt * 16 + quad * 4);
    uint2 u;
    u.x = pkbf(o[0] * inv, o[1] * inv);
    u.y = pkbf(o[2] * inv, o[3] * inv);
    *(uint2*)(ctx + rowb + nt * 16 + quad * 4) = u;
  }
}

// ---------------------------------------------------------------------------
extern "C" void kernel_launch(void* const* d_in, const int* in_sizes, int n_in,
                              void* d_out, int out_size, void* d_ws, size_t ws_size,
                              hipStream_t stream) {
  const float* q  = (const float*)d_in[0];
  const float* k  = (const float*)d_in[1];
  const float* v  = (const float*)d_in[2];
  // d_in[3] = causal mask (tril) — applied analytically, not read
  const float* Wq = (const float*)d_in[4];
  const float* bq = (const float*)d_in[5];
  const float* Wk = (const float*)d_in[6];
  const float* bk = (const float*)d_in[7];
  const float* Wv = (const float*)d_in[8];
  const float* bv = (const float*)d_in[9];
  const float* Wo = (const float*)d_in[10];
  const float* bo = (const float*)d_in[11];

  const size_t NTOK = (size_t)PB * PS * PE;   // 4,194,304 elems
  const size_t NW   = (size_t)PE * PE;        // 1,048,576 elems
  ushort* qh  = (ushort*)d_ws;
  ushort* kh  = qh + NTOK;
  ushort* vt  = kh + NTOK;
  ushort* qc  = vt + NTOK;
  ushort* kc  = qc + NTOK;
  ushort* vc  = kc + NTOK;
  ushort* wqc = vc + NTOK;
  ushort* wkc = wqc + NW;
  ushort* wvc = wkc + NW;
  ushort* woc = wvc + NW;
  ushort* ctx = qc;   // alias: qc is dead after qkv_kernel completes

  cvt_kernel<<<dim3(1024, 7), dim3(256), 0, stream>>>(
      q, k, v, Wq, Wk, Wv, Wo, qc, kc, vc, wqc, wkc, wvc, woc);
  qkv_kernel<<<dim3(32, 24), dim3(256), 0, stream>>>(
      qc, kc, vc, wqc, wkc, wvc, bq, bk, bv, qh, kh, vt);
  attn_kernel<<<dim3(32, 32), dim3(256), 0, stream>>>(qh, kh, vt, ctx);
  outproj_kernel<<<dim3(32, 8), dim3(256), 0, stream>>>(
      ctx, woc, bo, (float*)d_out);
}

// Round 7
// 217.267 us; speedup vs baseline: 1.7782x; 1.2078x over previous
//
#include <hip/hip_runtime.h>
#include <hip/hip_bf16.h>
#include <cstdint>

// Problem dims (fixed): B=2, S=2048, E=1024, H=16, D=64
#define PB 2
#define PS 2048
#define PE 1024
#define PH 16
#define PD 64

typedef __attribute__((ext_vector_type(8))) short short8;
typedef __attribute__((ext_vector_type(8))) ushort u16x8;
typedef __attribute__((ext_vector_type(4))) float f32x4;

static __device__ __forceinline__ float bf2f(ushort u) {
  return __uint_as_float(((unsigned)u) << 16);
}
static __device__ __forceinline__ ushort f2bf(float f) {
  unsigned u = __float_as_uint(f);
  u += 0x7fffu + ((u >> 16) & 1u);   // RNE
  return (ushort)(u >> 16);
}
// packed f32x2 -> bf16x2 (v_cvt_pk_bf16_f32 on gfx950 via HIP API)
static __device__ __forceinline__ unsigned pkbf(float a, float b) {
  __hip_bfloat162 h = __float22bfloat162_rn(make_float2(a, b));
  return *reinterpret_cast<unsigned*>(&h);
}
static __device__ __forceinline__ u16x8 cvt8(f32x4 a, f32x4 b) {
  union { unsigned u[4]; u16x8 v; } r;
  r.u[0] = pkbf(a[0], a[1]); r.u[1] = pkbf(a[2], a[3]);
  r.u[2] = pkbf(b[0], b[1]); r.u[3] = pkbf(b[2], b[3]);
  return r.v;
}

// CK-idiom async global->LDS 16B copy. LDS dest must be wave-uniform base.
static __device__ __forceinline__ void async16(void* lds, const void* g) {
  __attribute__((address_space(3))) unsigned* l =
      reinterpret_cast<__attribute__((address_space(3))) unsigned*>(
          reinterpret_cast<uintptr_t>(lds));
  const __attribute__((address_space(1))) unsigned* gp =
      reinterpret_cast<const __attribute__((address_space(1))) unsigned*>(
          reinterpret_cast<uintptr_t>(g));
  __builtin_amdgcn_global_load_lds(gp, l, 16, 0, 0);
}

// ---------------------------------------------------------------------------
// fp32 -> bf16 pre-conversion (x tensors + weights). blockIdx.y selects.
// 16 elems/thread.
// ---------------------------------------------------------------------------
__global__ __launch_bounds__(256)
void cvt_kernel(const float* __restrict__ s0, const float* __restrict__ s1,
                const float* __restrict__ s2, const float* __restrict__ s3,
                const float* __restrict__ s4, const float* __restrict__ s5,
                const float* __restrict__ s6,
                ushort* d0, ushort* d1, ushort* d2, ushort* d3, ushort* d4,
                ushort* d5, ushort* d6) {
  const int t = blockIdx.y;
  const float* src = t == 0 ? s0 : t == 1 ? s1 : t == 2 ? s2 : t == 3 ? s3
                   : t == 4 ? s4 : t == 5 ? s5 : s6;
  ushort* dst = t == 0 ? d0 : t == 1 ? d1 : t == 2 ? d2 : t == 3 ? d3
              : t == 4 ? d4 : t == 5 ? d5 : d6;
  const size_t n = (t < 3) ? (size_t)4194304 : (size_t)1048576;
  const size_t i0 = ((size_t)blockIdx.x * 256 + threadIdx.x) * 16;
  if (i0 >= n) return;
  const f32x4 a = *(const f32x4*)(src + i0);
  const f32x4 b = *(const f32x4*)(src + i0 + 4);
  const f32x4 c = *(const f32x4*)(src + i0 + 8);
  const f32x4 d = *(const f32x4*)(src + i0 + 12);
  *(u16x8*)(dst + i0) = cvt8(a, b);
  *(u16x8*)(dst + i0 + 8) = cvt8(c, d);
}

// ---------------------------------------------------------------------------
// GEMM core, bf16 A: BM=BN=128, BK=32, 4 waves 2x2, DOUBLE-BUFFERED LDS.
// ---------------------------------------------------------------------------
template <bool SWAP>
__device__ __forceinline__ void gemm_core(const ushort* __restrict__ A,
                                          const ushort* __restrict__ W,
                                          int m0, int n0,
                                          ushort* As, ushort* Bs,
                                          f32x4 acc[4][4]) {
  const int tid  = threadIdx.x;
  const int wave = tid >> 6;
  const int lane = tid & 63;
  const int quad = lane >> 4;
  const int lrow = lane & 15;
  const int wm = wave >> 1;
  const int wn = wave & 1;
  const int row0 = tid >> 2;
  const int kc8  = (tid & 3) * 8;

  auto stage = [&](int buf, int kt) {
    ushort* Ab = As + buf * 4096;
    ushort* Bb = Bs + buf * 4096;
    async16(Ab + (size_t)wave * 512,        A + (size_t)(m0 + row0)      * PE + kt + kc8);
    async16(Ab + 2048 + (size_t)wave * 512, A + (size_t)(m0 + row0 + 64) * PE + kt + kc8);
    async16(Bb + (size_t)wave * 512,        W + (size_t)(n0 + row0)      * PE + kt + kc8);
    async16(Bb + 2048 + (size_t)wave * 512, W + (size_t)(n0 + row0 + 64) * PE + kt + kc8);
  };

  stage(0, 0);
  __syncthreads();          // prologue drain: tile 0 resident
  int cur = 0;

  for (int kt = 0; kt < PE; kt += 32) {
    if (kt + 32 < PE) stage(cur ^ 1, kt + 32);   // in flight during compute
    const ushort* Ab = As + cur * 4096;
    short8 af[4], bf[4];
#pragma unroll
    for (int i = 0; i < 4; ++i) {
      af[i] = *(const short8*)(Ab + (wm * 64 + i * 16 + lrow) * 32 + quad * 8);
      bf[i] = *(const short8*)(Bs + cur * 4096 + (wn * 64 + i * 16 + lrow) * 32 + quad * 8);
    }
#pragma unroll
    for (int i = 0; i < 4; ++i)
#pragma unroll
      for (int j = 0; j < 4; ++j) {
        if (SWAP)
          acc[i][j] = __builtin_amdgcn_mfma_f32_16x16x32_bf16(bf[j], af[i], acc[i][j], 0, 0, 0);
        else
          acc[i][j] = __builtin_amdgcn_mfma_f32_16x16x32_bf16(af[i], bf[j], acc[i][j], 0, 0, 0);
      }
    __syncthreads();        // implicit vmcnt(0): t+1 landed; reads of cur done
    cur ^= 1;
  }
}

// ---------------------------------------------------------------------------
// Fused QKV projection (bf16 x, bf16 W). Q,K -> [B,H,S,D]; V -> [B,H,D,S].
// ---------------------------------------------------------------------------
__global__ __launch_bounds__(256)
void qkv_kernel(const ushort* __restrict__ q, const ushort* __restrict__ k,
                const ushort* __restrict__ v,
                const ushort* __restrict__ Wq, const ushort* __restrict__ Wk,
                const ushort* __restrict__ Wv,
                const float* __restrict__ bq, const float* __restrict__ bk,
                const float* __restrict__ bv,
                ushort* __restrict__ qh, ushort* __restrict__ kh,
                ushort* __restrict__ vt) {
  __shared__ __align__(16) ushort As[2 * 128 * 32];
  __shared__ __align__(16) ushort Bs[2 * 128 * 32];
  const int which = blockIdx.y >> 3;
  const int n0 = (blockIdx.y & 7) * 128;
  const int m0 = blockIdx.x * 128;
  const ushort* A  = which == 0 ? q  : (which == 1 ? k  : v);
  const ushort* W  = which == 0 ? Wq : (which == 1 ? Wk : Wv);
  const float* bi  = which == 0 ? bq : (which == 1 ? bk : bv);

  const int lane = threadIdx.x & 63;
  const int wave = threadIdx.x >> 6;
  const int quad = lane >> 4, lrow = lane & 15;
  const int wm = wave >> 1, wn = wave & 1;

  f32x4 acc[4][4] = {};
  if (which == 2) {
    gemm_core<true>(A, W, m0, n0, As, Bs, acc);
#pragma unroll
    for (int j = 0; j < 4; ++j) {
#pragma unroll
      for (int i = 0; i < 4; ++i) {
        const int xrow = m0 + wm * 64 + i * 16 + lrow;
        const int b = xrow >> 11, s = xrow & 2047;
#pragma unroll
        for (int r = 0; r < 4; ++r) {
          const int dcol = n0 + wn * 64 + j * 16 + quad * 4 + r;
          const int h = dcol >> 6, d = dcol & 63;
          vt[((size_t)((b << 4) + h) << 17) + ((size_t)d << 11) + s] =
              f2bf(acc[i][j][r] + bi[dcol]);
        }
      }
    }
  } else {
    gemm_core<false>(A, W, m0, n0, As, Bs, acc);
    ushort* Out = which == 0 ? qh : kh;
#pragma unroll
    for (int j = 0; j < 4; ++j) {
      const int col = n0 + wn * 64 + j * 16 + lrow;          // n in [0,1024)
      const float bias = bi[col];
      const int h = col >> 6, d = col & 63;
#pragma unroll
      for (int i = 0; i < 4; ++i)
#pragma unroll
        for (int r = 0; r < 4; ++r) {
          const int row = m0 + wm * 64 + i * 16 + quad * 4 + r;  // m in [0,4096)
          const int b = row >> 11, s = row & 2047;
          Out[((size_t)((b << 4) + h) << 17) + ((size_t)s << 6) + d] =
              f2bf(acc[i][j][r] + bias);
        }
    }
  }
}

// ---------------------------------------------------------------------------
// Output projection: out = ctx @ Wo^T + bo -> fp32 [4096,1024].
// ---------------------------------------------------------------------------
__global__ __launch_bounds__(256)
void outproj_kernel(const ushort* __restrict__ ctx, const ushort* __restrict__ Wo,
                    const float* __restrict__ bo, float* __restrict__ out) {
  __shared__ __align__(16) ushort As[2 * 128 * 32];
  __shared__ __align__(16) ushort Bs[2 * 128 * 32];
  const int n0 = blockIdx.y * 128;
  const int m0 = blockIdx.x * 128;

  f32x4 acc[4][4] = {};
  gemm_core<false>(ctx, Wo, m0, n0, As, Bs, acc);

  const int lane = threadIdx.x & 63;
  const int wave = threadIdx.x >> 6;
  const int quad = lane >> 4, lrow = lane & 15;
  const int wm = wave >> 1, wn = wave & 1;
#pragma unroll
  for (int j = 0; j < 4; ++j) {
    const int col = n0 + wn * 64 + j * 16 + lrow;
    const float bias = bo[col];
#pragma unroll
    for (int i = 0; i < 4; ++i)
#pragma unroll
      for (int r = 0; r < 4; ++r) {
        const int row = m0 + wm * 64 + i * 16 + quad * 4 + r;
        out[((size_t)row << 10) + col] = acc[i][j][r] + bias;
      }
  }
}

// ---------------------------------------------------------------------------
// MFMA causal flash attention — R3 structure (q-split, 4 blocks/CU, verified
// 42.6 µs) with ASYNC K/V STAGING (R6 post-mortem: key-split structures all
// lose to R3's TLP; the safe LDS-op cut is the staging path).
//  - global_load_lds with PRE-SWIZZLED per-lane global source (m173): linear
//    LDS dest (row, g') pulls global granule g'^(row&7); within each 8-row
//    stripe row&7 == lane>>3, so src granule = (lane&7)^(lane>>3). Deletes
//    4 ds_write_b128/lane-tile (26 -> 22 LDS ops), staging VALU, and 16
//    prefetch VGPRs. Same double-buffer schedule, one barrier per tile
//    (implicit vmcnt(0) is the drain) — identical to gemm_core's proven loop.
//  - s_setprio(1) around QK and PV MFMA clusters (T5; independent blocks at
//    different kt phases -> scheduler arbitration; attn-positive per m191).
//  - Balance perm (R3), l via ones-MFMA (R3), SOFF in C-init (R2) kept.
// ---------------------------------------------------------------------------
#define SW_IDX(r, g) (((r) << 6) + ((((g) ^ ((r) & 7))) << 3))
#define QSCALE 0.180336879f   /* 1/sqrt(64) * log2(e) */
#define SOFF 24.0f            /* static softmax offset (log2 domain) */

__global__ __launch_bounds__(256)
void attn_kernel(const ushort* __restrict__ qh, const ushort* __restrict__ kh,
                 const ushort* __restrict__ vt, ushort* __restrict__ ctx) {
  __shared__ __align__(16) ushort Ks[2][4096];
  __shared__ __align__(16) ushort Vs[2][4096];
  __shared__ __align__(16) ushort Ps[4][1024];   // wave-private 16q x 64k
  const int tid  = threadIdx.x;
  const int wave = tid >> 6;
  const int lane = tid & 63;
  const int quad = lane >> 4;
  const int lrow = lane & 15;
  const int bh = blockIdx.x, b = bh >> 4, h = bh & 15;
  const size_t base = (size_t)bh << 17;     // bh * S * D
  const int pr   = wave * 16 + lrow;        // this lane's q row in tile
  ushort* Pw = &Ps[wave][0];
  const int prow = lrow << 6;               // P row base (elements)

  // balance permutation: CU-resident {y,y+8,y+16,y+24} sum to 62
  const int y  = blockIdx.y;
  const int qb = (y < 8) ? 31 - y : (y < 16) ? y - 8 : (y < 24) ? 39 - y : y - 16;
  const int q0 = qb * 64;

  // async staging geometry: wave w stages rows w*16..w*16+15 of K and V^T
  // (2 async16 calls each, 8 rows/call). Linear LDS dest + swizzled source.
  const int w16  = wave * 16;
  const int rl   = lane >> 3;                       // row within 8-row stripe
  const int gsw  = ((lane & 7) ^ rl) << 3;          // swizzled src granule
  auto stageKV = [&](int buf, int kt) {
    const ushort* k0 = kh + base + (size_t)(kt * 64 + w16 + rl) * 64 + gsw;
    const ushort* k1 = kh + base + (size_t)(kt * 64 + w16 + 8 + rl) * 64 + gsw;
    async16(&Ks[buf][w16 << 6],       k0);
    async16(&Ks[buf][(w16 + 8) << 6], k1);
    const ushort* v0 = vt + base + (size_t)(w16 + rl) * 2048 + kt * 64 + gsw;
    const ushort* v1 = vt + base + (size_t)(w16 + 8 + rl) * 2048 + kt * 64 + gsw;
    async16(&Vs[buf][w16 << 6],       v0);
    async16(&Vs[buf][(w16 + 8) << 6], v1);
  };

  // Q B-fragments in registers, scaled by 1/sqrt(D)*log2(e)
  short8 qf0, qf1;
  {
    const ushort* qp = qh + base + (size_t)(q0 + pr) * 64 + quad * 8;
    const u16x8 a = *(const u16x8*)qp;
    const u16x8 c = *(const u16x8*)(qp + 32);
#pragma unroll
    for (int j = 0; j < 8; ++j) {
      qf0[j] = (short)f2bf(bf2f(a[j]) * QSCALE);
      qf1[j] = (short)f2bf(bf2f(c[j]) * QSCALE);
    }
  }

  // all-ones bf16 A-fragment for the l row-sum MFMA
  short8 ones;
#pragma unroll
  for (int j = 0; j < 8; ++j) ones[j] = (short)0x3F80;

  f32x4 o_acc[4] = {};
  f32x4 lacc = {};   // P row-sum accumulator (every slot holds the same sum)

  stageKV(0, 0);
  __syncthreads();   // prologue drain: tile 0 resident

  for (int kt = 0; kt <= qb; ++kt) {
    const int buf = kt & 1;
    if (kt < qb) stageKV(buf ^ 1, kt + 1);   // in flight during compute

    // S^T = mfma(K, Q): lane -> q=pr, keys nt*16+quad*4+r; C-init = -SOFF
    f32x4 st[4];
    __builtin_amdgcn_s_setprio(1);
#pragma unroll
    for (int nt = 0; nt < 4; ++nt) {
      const int r = nt * 16 + lrow;
      const short8 kb0 = *(const short8*)&Ks[buf][SW_IDX(r, quad)];
      const short8 kb1 = *(const short8*)&Ks[buf][SW_IDX(r, quad + 4)];
      st[nt] = (f32x4){-SOFF, -SOFF, -SOFF, -SOFF};
      st[nt] = __builtin_amdgcn_mfma_f32_16x16x32_bf16(kb0, qf0, st[nt], 0, 0, 0);
      st[nt] = __builtin_amdgcn_mfma_f32_16x16x32_bf16(kb1, qf1, st[nt], 0, 0, 0);
    }
    __builtin_amdgcn_s_setprio(0);

    if (kt == qb) {    // causal mask on diagonal tile (local coords)
#pragma unroll
      for (int nt = 0; nt < 4; ++nt)
#pragma unroll
        for (int r = 0; r < 4; ++r)
          if (nt * 16 + quad * 4 + r > pr) st[nt][r] = -1e30f;
    }

    // static-offset softmax: p = exp2(st) (SOFF already folded into C-init)
#pragma unroll
    for (int nt = 0; nt < 4; ++nt) {
      float p0 = exp2f(st[nt][0]);
      float p1 = exp2f(st[nt][1]);
      float p2 = exp2f(st[nt][2]);
      float p3 = exp2f(st[nt][3]);
      uint2 pk;
      pk.x = pkbf(p0, p1); pk.y = pkbf(p2, p3);
      // keys nt*16+quad*4+[0..3]; granule = nt*2+(quad>>1), offs (quad&1)*4
      *(uint2*)&Pw[prow + (((nt * 2 + (quad >> 1)) ^ (lrow & 7)) << 3) +
                   (quad & 1) * 4] = pk;
    }

    // PV: O^T = mfma(V^T, P): lane -> q=pr, d = nt*16+quad*4+r
    const short8 pa0 = *(const short8*)&Pw[prow + ((quad ^ (lrow & 7)) << 3)];
    const short8 pa1 = *(const short8*)&Pw[prow + (((quad + 4) ^ (lrow & 7)) << 3)];
    __builtin_amdgcn_s_setprio(1);
    // l row-sum on the MFMA pipe: A=ones -> out[q][*] = sum_k P[q][k]
    lacc = __builtin_amdgcn_mfma_f32_16x16x32_bf16(ones, pa0, lacc, 0, 0, 0);
    lacc = __builtin_amdgcn_mfma_f32_16x16x32_bf16(ones, pa1, lacc, 0, 0, 0);
#pragma unroll
    for (int nt = 0; nt < 4; ++nt) {
      const int r = nt * 16 + lrow;
      const short8 vb0 = *(const short8*)&Vs[buf][SW_IDX(r, quad)];
      const short8 vb1 = *(const short8*)&Vs[buf][SW_IDX(r, quad + 4)];
      o_acc[nt] = __builtin_amdgcn_mfma_f32_16x16x32_bf16(vb0, pa0, o_acc[nt], 0, 0, 0);
      o_acc[nt] = __builtin_amdgcn_mfma_f32_16x16x32_bf16(vb1, pa1, o_acc[nt], 0, 0, 0);
    }
    __builtin_amdgcn_s_setprio(0);
    __syncthreads();   // drains vmcnt (next tile landed) + all reads of buf done
  }

  // epilogue: ctx [B,S,E] bf16, packed 8B stores
  const float inv = 1.f / lacc[0];
  const size_t rowb = ((size_t)b << 21) + ((size_t)(q0 + pr) << 10) + (h << 6);
#pragma unroll
  for (int nt = 0; nt < 4; ++nt) {
    uint2 u;
    u.x = pkbf(o_acc[nt][0] * inv, o_acc[nt][1] * inv);
    u.y = pkbf(o_acc[nt][2] * inv, o_acc[nt][3] * inv);
    *(uint2*)(ctx + rowb + nt * 16 + quad * 4) = u;
  }
}

// ---------------------------------------------------------------------------
extern "C" void kernel_launch(void* const* d_in, const int* in_sizes, int n_in,
                              void* d_out, int out_size, void* d_ws, size_t ws_size,
                              hipStream_t stream) {
  const float* q  = (const float*)d_in[0];
  const float* k  = (const float*)d_in[1];
  const float* v  = (const float*)d_in[2];
  // d_in[3] = causal mask (tril) — applied analytically, not read
  const float* Wq = (const float*)d_in[4];
  const float* bq = (const float*)d_in[5];
  const float* Wk = (const float*)d_in[6];
  const float* bk = (const float*)d_in[7];
  const float* Wv = (const float*)d_in[8];
  const float* bv = (const float*)d_in[9];
  const float* Wo = (const float*)d_in[10];
  const float* bo = (const float*)d_in[11];

  const size_t NTOK = (size_t)PB * PS * PE;   // 4,194,304 elems
  const size_t NW   = (size_t)PE * PE;        // 1,048,576 elems
  ushort* qh  = (ushort*)d_ws;
  ushort* kh  = qh + NTOK;
  ushort* vt  = kh + NTOK;
  ushort* qc  = vt + NTOK;
  ushort* kc  = qc + NTOK;
  ushort* vc  = kc + NTOK;
  ushort* wqc = vc + NTOK;
  ushort* wkc = wqc + NW;
  ushort* wvc = wkc + NW;
  ushort* woc = wvc + NW;
  ushort* ctx = qc;   // alias: qc is dead after qkv_kernel completes

  cvt_kernel<<<dim3(1024, 7), dim3(256), 0, stream>>>(
      q, k, v, Wq, Wk, Wv, Wo, qc, kc, vc, wqc, wkc, wvc, woc);
  qkv_kernel<<<dim3(32, 24), dim3(256), 0, stream>>>(
      qc, kc, vc, wqc, wkc, wvc, bq, bk, bv, qh, kh, vt);
  attn_kernel<<<dim3(32, 32), dim3(256), 0, stream>>>(qh, kh, vt, ctx);
  outproj_kernel<<<dim3(32, 8), dim3(256), 0, stream>>>(
      ctx, woc, bo, (float*)d_out);
}

// Round 8
// 213.679 us; speedup vs baseline: 1.8080x; 1.0168x over previous
//
#include <hip/hip_runtime.h>
#include <hip/hip_bf16.h>
#include <cstdint>

// Problem dims (fixed): B=2, S=2048, E=1024, H=16, D=64
#define PB 2
#define PS 2048
#define PE 1024
#define PH 16
#define PD 64

typedef __attribute__((ext_vector_type(8))) short short8;
typedef __attribute__((ext_vector_type(8))) ushort u16x8;
typedef __attribute__((ext_vector_type(4))) float f32x4;

static __device__ __forceinline__ float bf2f(ushort u) {
  return __uint_as_float(((unsigned)u) << 16);
}
static __device__ __forceinline__ ushort f2bf(float f) {
  unsigned u = __float_as_uint(f);
  u += 0x7fffu + ((u >> 16) & 1u);   // RNE
  return (ushort)(u >> 16);
}
// packed f32x2 -> bf16x2 (v_cvt_pk_bf16_f32 on gfx950 via HIP API)
static __device__ __forceinline__ unsigned pkbf(float a, float b) {
  __hip_bfloat162 h = __float22bfloat162_rn(make_float2(a, b));
  return *reinterpret_cast<unsigned*>(&h);
}
static __device__ __forceinline__ u16x8 cvt8(f32x4 a, f32x4 b) {
  union { unsigned u[4]; u16x8 v; } r;
  r.u[0] = pkbf(a[0], a[1]); r.u[1] = pkbf(a[2], a[3]);
  r.u[2] = pkbf(b[0], b[1]); r.u[3] = pkbf(b[2], b[3]);
  return r.v;
}

// CK-idiom async global->LDS 16B copy. LDS dest must be wave-uniform base.
static __device__ __forceinline__ void async16(void* lds, const void* g) {
  __attribute__((address_space(3))) unsigned* l =
      reinterpret_cast<__attribute__((address_space(3))) unsigned*>(
          reinterpret_cast<uintptr_t>(lds));
  const __attribute__((address_space(1))) unsigned* gp =
      reinterpret_cast<const __attribute__((address_space(1))) unsigned*>(
          reinterpret_cast<uintptr_t>(g));
  __builtin_amdgcn_global_load_lds(gp, l, 16, 0, 0);
}

// ---------------------------------------------------------------------------
// fp32 -> bf16 pre-conversion (x tensors + weights). blockIdx.y selects.
// 16 elems/thread.
// ---------------------------------------------------------------------------
__global__ __launch_bounds__(256)
void cvt_kernel(const float* __restrict__ s0, const float* __restrict__ s1,
                const float* __restrict__ s2, const float* __restrict__ s3,
                const float* __restrict__ s4, const float* __restrict__ s5,
                const float* __restrict__ s6,
                ushort* d0, ushort* d1, ushort* d2, ushort* d3, ushort* d4,
                ushort* d5, ushort* d6) {
  const int t = blockIdx.y;
  const float* src = t == 0 ? s0 : t == 1 ? s1 : t == 2 ? s2 : t == 3 ? s3
                   : t == 4 ? s4 : t == 5 ? s5 : s6;
  ushort* dst = t == 0 ? d0 : t == 1 ? d1 : t == 2 ? d2 : t == 3 ? d3
              : t == 4 ? d4 : t == 5 ? d5 : d6;
  const size_t n = (t < 3) ? (size_t)4194304 : (size_t)1048576;
  const size_t i0 = ((size_t)blockIdx.x * 256 + threadIdx.x) * 16;
  if (i0 >= n) return;
  const f32x4 a = *(const f32x4*)(src + i0);
  const f32x4 b = *(const f32x4*)(src + i0 + 4);
  const f32x4 c = *(const f32x4*)(src + i0 + 8);
  const f32x4 d = *(const f32x4*)(src + i0 + 12);
  *(u16x8*)(dst + i0) = cvt8(a, b);
  *(u16x8*)(dst + i0 + 8) = cvt8(c, d);
}

// ---------------------------------------------------------------------------
// GEMM core, bf16 A: BM=BN=128, BK=32, 4 waves 2x2, now a 3-STAGE PIPELINE
// (R7 post-mortem: per-iter wall 3570 cyc vs ~500 cyc work at all-pipes-idle
// counters = exposed global->LDS latency; the 2-buffer barrier drain gave
// tile t+1 only one compute window of flight time).
// Loop t: stage(t+2) -> s_waitcnt vmcnt(8) (tile t's 4 per-wave loads, issued
// TWO iters ago, must land; t+1/t+2 stay in flight across the barrier) ->
// s_barrier -> compute(t) -> s_barrier (fences buf[t%3] reuse by stage(t+3)).
// Tail drains vmcnt 8->4->0. Buffer index is address-only (rule #20 safe).
// LDS 3 bufs x (A 8KB + B 8KB) = 48KB -> qkv stays 3 blocks/CU.
// SWAP=false: acc[i][j] = C[m=x-rows i][n=W-rows j] (normal).
// SWAP=true : acc[i][j] = C[m=W-rows j][n=x-rows i] (transposed output).
// ---------------------------------------------------------------------------
template <bool SWAP>
__device__ __forceinline__ void gemm_core(const ushort* __restrict__ A,
                                          const ushort* __restrict__ W,
                                          int m0, int n0,
                                          ushort* As, ushort* Bs,
                                          f32x4 acc[4][4]) {
  const int tid  = threadIdx.x;
  const int wave = tid >> 6;
  const int lane = tid & 63;
  const int quad = lane >> 4;
  const int lrow = lane & 15;
  const int wm = wave >> 1;
  const int wn = wave & 1;
  const int row0 = tid >> 2;
  const int kc8  = (tid & 3) * 8;

  // stage K-step (kt) into buffer buf: 4 async16 per wave (A lo/hi, B lo/hi)
  auto stage = [&](int buf, int kt) {
    ushort* Ab = As + buf * 4096;
    ushort* Bb = Bs + buf * 4096;
    async16(Ab + (size_t)wave * 512,        A + (size_t)(m0 + row0)      * PE + kt + kc8);
    async16(Ab + 2048 + (size_t)wave * 512, A + (size_t)(m0 + row0 + 64) * PE + kt + kc8);
    async16(Bb + (size_t)wave * 512,        W + (size_t)(n0 + row0)      * PE + kt + kc8);
    async16(Bb + 2048 + (size_t)wave * 512, W + (size_t)(n0 + row0 + 64) * PE + kt + kc8);
  };

  stage(0, 0);
  stage(1, 32);
  int cb = 0;                       // compute buffer = t % 3 (address-only)

  for (int t = 0; t < 32; ++t) {
    if (t + 2 < 32) {
      const int sb = (cb == 0) ? 2 : cb - 1;   // (t+2) % 3
      stage(sb, (t + 2) * 32);
      asm volatile("s_waitcnt vmcnt(8)" ::: "memory");   // tile t landed
    } else if (t + 1 < 32) {
      asm volatile("s_waitcnt vmcnt(4)" ::: "memory");
    } else {
      asm volatile("s_waitcnt vmcnt(0)" ::: "memory");
    }
    __builtin_amdgcn_s_barrier();   // all waves' t-loads in LDS

    const ushort* Ab = As + cb * 4096;
    const ushort* Bb = Bs + cb * 4096;
    short8 af[4], bf[4];
#pragma unroll
    for (int i = 0; i < 4; ++i) {
      af[i] = *(const short8*)(Ab + (wm * 64 + i * 16 + lrow) * 32 + quad * 8);
      bf[i] = *(const short8*)(Bb + (wn * 64 + i * 16 + lrow) * 32 + quad * 8);
    }
#pragma unroll
    for (int i = 0; i < 4; ++i)
#pragma unroll
      for (int j = 0; j < 4; ++j) {
        if (SWAP)
          acc[i][j] = __builtin_amdgcn_mfma_f32_16x16x32_bf16(bf[j], af[i], acc[i][j], 0, 0, 0);
        else
          acc[i][j] = __builtin_amdgcn_mfma_f32_16x16x32_bf16(af[i], bf[j], acc[i][j], 0, 0, 0);
      }
    __builtin_amdgcn_s_barrier();   // reads of buf cb done -> stage may reuse
    cb = (cb == 2) ? 0 : cb + 1;
  }
}

// ---------------------------------------------------------------------------
// Fused QKV projection (bf16 x, bf16 W). Q,K -> [B,H,S,D]; V -> [B,H,D,S].
// Grid (x=m0, y=which*8+n0): n0-siblings sharing an A-strip land on the same
// XCD (ids differ by 32 == 0 mod 8) -> A served from that XCD's L2.
// ---------------------------------------------------------------------------
__global__ __launch_bounds__(256)
void qkv_kernel(const ushort* __restrict__ q, const ushort* __restrict__ k,
                const ushort* __restrict__ v,
                const ushort* __restrict__ Wq, const ushort* __restrict__ Wk,
                const ushort* __restrict__ Wv,
                const float* __restrict__ bq, const float* __restrict__ bk,
                const float* __restrict__ bv,
                ushort* __restrict__ qh, ushort* __restrict__ kh,
                ushort* __restrict__ vt) {
  __shared__ __align__(16) ushort As[3 * 128 * 32];
  __shared__ __align__(16) ushort Bs[3 * 128 * 32];
  const int which = blockIdx.y >> 3;
  const int n0 = (blockIdx.y & 7) * 128;
  const int m0 = blockIdx.x * 128;
  const ushort* A  = which == 0 ? q  : (which == 1 ? k  : v);
  const ushort* W  = which == 0 ? Wq : (which == 1 ? Wk : Wv);
  const float* bi  = which == 0 ? bq : (which == 1 ? bk : bv);

  const int lane = threadIdx.x & 63;
  const int wave = threadIdx.x >> 6;
  const int quad = lane >> 4, lrow = lane & 15;
  const int wm = wave >> 1, wn = wave & 1;

  f32x4 acc[4][4] = {};
  if (which == 2) {
    gemm_core<true>(A, W, m0, n0, As, Bs, acc);
    // acc[i][j]: C[m=W-row tile j][n=x-row tile i]; col=lane&15 -> x-row,
    // row=quad*4+r -> W-row (d-col). Store V^T [B,H,D,S].
#pragma unroll
    for (int j = 0; j < 4; ++j) {
#pragma unroll
      for (int i = 0; i < 4; ++i) {
        const int xrow = m0 + wm * 64 + i * 16 + lrow;
        const int b = xrow >> 11, s = xrow & 2047;
#pragma unroll
        for (int r = 0; r < 4; ++r) {
          const int dcol = n0 + wn * 64 + j * 16 + quad * 4 + r;
          const int h = dcol >> 6, d = dcol & 63;
          vt[((size_t)((b << 4) + h) << 17) + ((size_t)d << 11) + s] =
              f2bf(acc[i][j][r] + bi[dcol]);
        }
      }
    }
  } else {
    gemm_core<false>(A, W, m0, n0, As, Bs, acc);
    ushort* Out = which == 0 ? qh : kh;
#pragma unroll
    for (int j = 0; j < 4; ++j) {
      const int col = n0 + wn * 64 + j * 16 + lrow;          // n in [0,1024)
      const float bias = bi[col];
      const int h = col >> 6, d = col & 63;
#pragma unroll
      for (int i = 0; i < 4; ++i)
#pragma unroll
        for (int r = 0; r < 4; ++r) {
          const int row = m0 + wm * 64 + i * 16 + quad * 4 + r;  // m in [0,4096)
          const int b = row >> 11, s = row & 2047;
          Out[((size_t)((b << 4) + h) << 17) + ((size_t)s << 6) + d] =
              f2bf(acc[i][j][r] + bias);
        }
    }
  }
}

// ---------------------------------------------------------------------------
// Output projection: out = ctx @ Wo^T + bo -> fp32 [4096,1024].
// Grid (x=m0 32, y=n0 8): n0-siblings same XCD (ids differ by 32).
// 1 block/CU -> the 3-stage pipeline matters most here (no cross-block TLP).
// ---------------------------------------------------------------------------
__global__ __launch_bounds__(256)
void outproj_kernel(const ushort* __restrict__ ctx, const ushort* __restrict__ Wo,
                    const float* __restrict__ bo, float* __restrict__ out) {
  __shared__ __align__(16) ushort As[3 * 128 * 32];
  __shared__ __align__(16) ushort Bs[3 * 128 * 32];
  const int n0 = blockIdx.y * 128;
  const int m0 = blockIdx.x * 128;

  f32x4 acc[4][4] = {};
  gemm_core<false>(ctx, Wo, m0, n0, As, Bs, acc);

  const int lane = threadIdx.x & 63;
  const int wave = threadIdx.x >> 6;
  const int quad = lane >> 4, lrow = lane & 15;
  const int wm = wave >> 1, wn = wave & 1;
#pragma unroll
  for (int j = 0; j < 4; ++j) {
    const int col = n0 + wn * 64 + j * 16 + lrow;
    const float bias = bo[col];
#pragma unroll
    for (int i = 0; i < 4; ++i)
#pragma unroll
      for (int r = 0; r < 4; ++r) {
        const int row = m0 + wm * 64 + i * 16 + quad * 4 + r;
        out[((size_t)row << 10) + col] = acc[i][j][r] + bias;
      }
  }
}

// ---------------------------------------------------------------------------
// MFMA causal flash attention — unchanged from R7 (q-split, 4 blocks/CU,
// async K/V staging with pre-swizzled global source, setprio around MFMA
// clusters, balance perm, ones-MFMA l, SOFF in C-init).
// ---------------------------------------------------------------------------
#define SW_IDX(r, g) (((r) << 6) + ((((g) ^ ((r) & 7))) << 3))
#define QSCALE 0.180336879f   /* 1/sqrt(64) * log2(e) */
#define SOFF 24.0f            /* static softmax offset (log2 domain) */

__global__ __launch_bounds__(256)
void attn_kernel(const ushort* __restrict__ qh, const ushort* __restrict__ kh,
                 const ushort* __restrict__ vt, ushort* __restrict__ ctx) {
  __shared__ __align__(16) ushort Ks[2][4096];
  __shared__ __align__(16) ushort Vs[2][4096];
  __shared__ __align__(16) ushort Ps[4][1024];   // wave-private 16q x 64k
  const int tid  = threadIdx.x;
  const int wave = tid >> 6;
  const int lane = tid & 63;
  const int quad = lane >> 4;
  const int lrow = lane & 15;
  const int bh = blockIdx.x, b = bh >> 4, h = bh & 15;
  const size_t base = (size_t)bh << 17;     // bh * S * D
  const int pr   = wave * 16 + lrow;        // this lane's q row in tile
  ushort* Pw = &Ps[wave][0];
  const int prow = lrow << 6;               // P row base (elements)

  // balance permutation: CU-resident {y,y+8,y+16,y+24} sum to 62
  const int y  = blockIdx.y;
  const int qb = (y < 8) ? 31 - y : (y < 16) ? y - 8 : (y < 24) ? 39 - y : y - 16;
  const int q0 = qb * 64;

  // async staging geometry: wave w stages rows w*16..w*16+15 of K and V^T
  // (2 async16 calls each, 8 rows/call). Linear LDS dest + swizzled source.
  const int w16  = wave * 16;
  const int rl   = lane >> 3;                       // row within 8-row stripe
  const int gsw  = ((lane & 7) ^ rl) << 3;          // swizzled src granule
  auto stageKV = [&](int buf, int kt) {
    const ushort* k0 = kh + base + (size_t)(kt * 64 + w16 + rl) * 64 + gsw;
    const ushort* k1 = kh + base + (size_t)(kt * 64 + w16 + 8 + rl) * 64 + gsw;
    async16(&Ks[buf][w16 << 6],       k0);
    async16(&Ks[buf][(w16 + 8) << 6], k1);
    const ushort* v0 = vt + base + (size_t)(w16 + rl) * 2048 + kt * 64 + gsw;
    const ushort* v1 = vt + base + (size_t)(w16 + 8 + rl) * 2048 + kt * 64 + gsw;
    async16(&Vs[buf][w16 << 6],       v0);
    async16(&Vs[buf][(w16 + 8) << 6], v1);
  };

  // Q B-fragments in registers, scaled by 1/sqrt(D)*log2(e)
  short8 qf0, qf1;
  {
    const ushort* qp = qh + base + (size_t)(q0 + pr) * 64 + quad * 8;
    const u16x8 a = *(const u16x8*)qp;
    const u16x8 c = *(const u16x8*)(qp + 32);
#pragma unroll
    for (int j = 0; j < 8; ++j) {
      qf0[j] = (short)f2bf(bf2f(a[j]) * QSCALE);
      qf1[j] = (short)f2bf(bf2f(c[j]) * QSCALE);
    }
  }

  // all-ones bf16 A-fragment for the l row-sum MFMA
  short8 ones;
#pragma unroll
  for (int j = 0; j < 8; ++j) ones[j] = (short)0x3F80;

  f32x4 o_acc[4] = {};
  f32x4 lacc = {};   // P row-sum accumulator (every slot holds the same sum)

  stageKV(0, 0);
  __syncthreads();   // prologue drain: tile 0 resident

  for (int kt = 0; kt <= qb; ++kt) {
    const int buf = kt & 1;
    if (kt < qb) stageKV(buf ^ 1, kt + 1);   // in flight during compute

    // S^T = mfma(K, Q): lane -> q=pr, keys nt*16+quad*4+r; C-init = -SOFF
    f32x4 st[4];
    __builtin_amdgcn_s_setprio(1);
#pragma unroll
    for (int nt = 0; nt < 4; ++nt) {
      const int r = nt * 16 + lrow;
      const short8 kb0 = *(const short8*)&Ks[buf][SW_IDX(r, quad)];
      const short8 kb1 = *(const short8*)&Ks[buf][SW_IDX(r, quad + 4)];
      st[nt] = (f32x4){-SOFF, -SOFF, -SOFF, -SOFF};
      st[nt] = __builtin_amdgcn_mfma_f32_16x16x32_bf16(kb0, qf0, st[nt], 0, 0, 0);
      st[nt] = __builtin_amdgcn_mfma_f32_16x16x32_bf16(kb1, qf1, st[nt], 0, 0, 0);
    }
    __builtin_amdgcn_s_setprio(0);

    if (kt == qb) {    // causal mask on diagonal tile (local coords)
#pragma unroll
      for (int nt = 0; nt < 4; ++nt)
#pragma unroll
        for (int r = 0; r < 4; ++r)
          if (nt * 16 + quad * 4 + r > pr) st[nt][r] = -1e30f;
    }

    // static-offset softmax: p = exp2(st) (SOFF already folded into C-init)
#pragma unroll
    for (int nt = 0; nt < 4; ++nt) {
      float p0 = exp2f(st[nt][0]);
      float p1 = exp2f(st[nt][1]);
      float p2 = exp2f(st[nt][2]);
      float p3 = exp2f(st[nt][3]);
      uint2 pk;
      pk.x = pkbf(p0, p1); pk.y = pkbf(p2, p3);
      // keys nt*16+quad*4+[0..3]; granule = nt*2+(quad>>1), offs (quad&1)*4
      *(uint2*)&Pw[prow + (((nt * 2 + (quad >> 1)) ^ (lrow & 7)) << 3) +
                   (quad & 1) * 4] = pk;
    }

    // PV: O^T = mfma(V^T, P): lane -> q=pr, d = nt*16+quad*4+r
    const short8 pa0 = *(const short8*)&Pw[prow + ((quad ^ (lrow & 7)) << 3)];
    const short8 pa1 = *(const short8*)&Pw[prow + (((quad + 4) ^ (lrow & 7)) << 3)];
    __builtin_amdgcn_s_setprio(1);
    // l row-sum on the MFMA pipe: A=ones -> out[q][*] = sum_k P[q][k]
    lacc = __builtin_amdgcn_mfma_f32_16x16x32_bf16(ones, pa0, lacc, 0, 0, 0);
    lacc = __builtin_amdgcn_mfma_f32_16x16x32_bf16(ones, pa1, lacc, 0, 0, 0);
#pragma unroll
    for (int nt = 0; nt < 4; ++nt) {
      const int r = nt * 16 + lrow;
      const short8 vb0 = *(const short8*)&Vs[buf][SW_IDX(r, quad)];
      const short8 vb1 = *(const short8*)&Vs[buf][SW_IDX(r, quad + 4)];
      o_acc[nt] = __builtin_amdgcn_mfma_f32_16x16x32_bf16(vb0, pa0, o_acc[nt], 0, 0, 0);
      o_acc[nt] = __builtin_amdgcn_mfma_f32_16x16x32_bf16(vb1, pa1, o_acc[nt], 0, 0, 0);
    }
    __builtin_amdgcn_s_setprio(0);
    __syncthreads();   // drains vmcnt (next tile landed) + all reads of buf done
  }

  // epilogue: ctx [B,S,E] bf16, packed 8B stores
  const float inv = 1.f / lacc[0];
  const size_t rowb = ((size_t)b << 21) + ((size_t)(q0 + pr) << 10) + (h << 6);
#pragma unroll
  for (int nt = 0; nt < 4; ++nt) {
    uint2 u;
    u.x = pkbf(o_acc[nt][0] * inv, o_acc[nt][1] * inv);
    u.y = pkbf(o_acc[nt][2] * inv, o_acc[nt][3] * inv);
    *(uint2*)(ctx + rowb + nt * 16 + quad * 4) = u;
  }
}

// ---------------------------------------------------------------------------
extern "C" void kernel_launch(void* const* d_in, const int* in_sizes, int n_in,
                              void* d_out, int out_size, void* d_ws, size_t ws_size,
                              hipStream_t stream) {
  const float* q  = (const float*)d_in[0];
  const float* k  = (const float*)d_in[1];
  const float* v  = (const float*)d_in[2];
  // d_in[3] = causal mask (tril) — applied analytically, not read
  const float* Wq = (const float*)d_in[4];
  const float* bq = (const float*)d_in[5];
  const float* Wk = (const float*)d_in[6];
  const float* bk = (const float*)d_in[7];
  const float* Wv = (const float*)d_in[8];
  const float* bv = (const float*)d_in[9];
  const float* Wo = (const float*)d_in[10];
  const float* bo = (const float*)d_in[11];

  const size_t NTOK = (size_t)PB * PS * PE;   // 4,194,304 elems
  const size_t NW   = (size_t)PE * PE;        // 1,048,576 elems
  ushort* qh  = (ushort*)d_ws;
  ushort* kh  = qh + NTOK;
  ushort* vt  = kh + NTOK;
  ushort* qc  = vt + NTOK;
  ushort* kc  = qc + NTOK;
  ushort* vc  = kc + NTOK;
  ushort* wqc = vc + NTOK;
  ushort* wkc = wqc + NW;
  ushort* wvc = wkc + NW;
  ushort* woc = wvc + NW;
  ushort* ctx = qc;   // alias: qc is dead after qkv_kernel completes

  cvt_kernel<<<dim3(1024, 7), dim3(256), 0, stream>>>(
      q, k, v, Wq, Wk, Wv, Wo, qc, kc, vc, wqc, wkc, wvc, woc);
  qkv_kernel<<<dim3(32, 24), dim3(256), 0, stream>>>(
      qc, kc, vc, wqc, wkc, wvc, bq, bk, bv, qh, kh, vt);
  attn_kernel<<<dim3(32, 32), dim3(256), 0, stream>>>(qh, kh, vt, ctx);
  outproj_kernel<<<dim3(32, 8), dim3(256), 0, stream>>>(
      ctx, woc, bo, (float*)d_out);
}